// Round 11
// baseline (426.571 us; speedup 1.0000x reference)
//
#include <hip/hip_runtime.h>
#include <hip/hip_bf16.h>

typedef __bf16 bf16x8 __attribute__((ext_vector_type(8)));
typedef float  f32x4  __attribute__((ext_vector_type(4)));

#define DIM    512
#define DINNER 1024
#define SEQL   256
#define NLAYER 7    // layer 7's mixer output is discarded by the reference
#define LPAD   260  // [.][l] LDS row stride: 260%32==4 -> staggered banks
#define NCH    8
#define CLEN   32

#define N4WI (NLAYER * 2048 * 512 / 4)
#define N4WX (NLAYER * 64 * 1024 / 4)
#define N4WO (NLAYER * 512 * 1024 / 4)
#define N4ALL (N4WI + N4WX + N4WO)          // 2,867,200
#define NCASTB (N4ALL / 256)                // 11200 blocks

// ---------------- merged: weight casts + input transpose ----------------
__global__ __launch_bounds__(256) void k_castin(const float* __restrict__ Wi,
                                                const float* __restrict__ Wx,
                                                const float* __restrict__ Wo,
                                                const float* __restrict__ x,
                                                __hip_bfloat16* __restrict__ wib,
                                                __hip_bfloat16* __restrict__ wxb,
                                                __hip_bfloat16* __restrict__ wob,
                                                float* __restrict__ res) {
  if (blockIdx.x >= NCASTB) {   // transpose region: 1024 blocks
    int idx = (blockIdx.x - NCASTB) * 256 + threadIdx.x;   // B*L*DIM = 262144
    int d = idx & (DIM - 1), l = (idx >> 9) & (SEQL - 1), b = idx >> 17;
    res[idx] = x[((size_t)((b << 9) + d) << 8) + l];
    return;
  }
  int i = blockIdx.x * 256 + threadIdx.x;
  const float* src; __hip_bfloat16* dst; int j;
  if (i < N4WI)             { src = Wi; dst = wib; j = i; }
  else if (i < N4WI + N4WX) { src = Wx; dst = wxb; j = i - N4WI; }
  else                      { src = Wo; dst = wob; j = i - N4WI - N4WX; }
  float4 v = reinterpret_cast<const float4*>(src)[j];
  struct alignas(8) B4 { __hip_bfloat16 a, b, c, d; };
  B4 o{ (__hip_bfloat16)v.x, (__hip_bfloat16)v.y, (__hip_bfloat16)v.z, (__hip_bfloat16)v.w };
  reinterpret_cast<B4*>(dst)[j] = o;
}

// ========== k1: rmsnorm + in_proj (48x128 LDS tile) + conv + silu ==========
// (round-6/9/10 verified configuration, unchanged)
__global__ __launch_bounds__(1024) void k_front(const float* __restrict__ res,
                                                const float* __restrict__ nwL,
                                                const __hip_bfloat16* __restrict__ wiL,
                                                const float4* __restrict__ cwL,
                                                const float* __restrict__ cbL,
                                                __hip_bfloat16* __restrict__ xcb,
                                                float* __restrict__ xcT,
                                                float* __restrict__ zT) {
  __shared__ __align__(16) char smem[75264];
  __hip_bfloat16 (*s_hn)[520] = (__hip_bfloat16(*)[520])smem;   // 49920B
  float (*s_xz)[132] = (float(*)[132])(smem + 49920);           // 25344B
  float (*s_sv)[68]  = (float(*)[68])smem;                      // aliases s_hn
  const int tid = threadIdx.x, bid = blockIdx.x;
  const int wid = tid >> 6, lane = tid & 63;
  const int r = lane & 15, g = lane >> 4;
  const int ttile = bid >> 4, sl = bid & 15;
  const int t0 = ttile * 32, m0 = t0 - 3;
#pragma unroll
  for (int k = 0; k < 3; ++k) {
    int rw = wid * 3 + k;
    int grc = min(max(m0 + rw, 0), 511);
    const float* rr = res + ((size_t)grc << 9);
    float v[8]; float ssum = 0.f;
#pragma unroll
    for (int j2 = 0; j2 < 8; ++j2) { v[j2] = rr[lane + (j2 << 6)]; ssum = fmaf(v[j2], v[j2], ssum); }
#pragma unroll
    for (int m = 1; m < 64; m <<= 1) ssum += __shfl_xor(ssum, m);
    float inv = rsqrtf(ssum * (1.0f / 512.0f) + 1e-5f);
#pragma unroll
    for (int j2 = 0; j2 < 8; ++j2)
      s_hn[rw][lane + (j2 << 6)] = (__hip_bfloat16)(v[j2] * inv * nwL[lane + (j2 << 6)]);
  }
  __syncthreads();
  for (int j = wid; j < 24; j += 16) {
    int mf = j >> 3, cf = j & 7;
    int gcol = (cf < 4) ? (sl * 64 + cf * 16 + r) : (1024 + sl * 64 + (cf - 4) * 16 + r);
    const bf16x8* pb = reinterpret_cast<const bf16x8*>(wiL + (size_t)gcol * 512) + g;
    f32x4 acc = {0.f, 0.f, 0.f, 0.f};
#pragma unroll
    for (int kc = 0; kc < 16; ++kc) {
      bf16x8 a = *reinterpret_cast<const bf16x8*>(&s_hn[mf * 16 + r][kc * 32 + g * 8]);
      acc = __builtin_amdgcn_mfma_f32_16x16x32_bf16(a, pb[kc * 4], acc, 0, 0, 0);
    }
    int cc = (cf < 4) ? (cf * 16 + r) : (64 + (cf - 4) * 16 + r);
#pragma unroll
    for (int jj = 0; jj < 4; ++jj) s_xz[mf * 16 + g * 4 + jj][cc] = acc[jj];
  }
  __syncthreads();
  const int t0s = t0 & 255;
#pragma unroll
  for (int k = 0; k < 2; ++k) {
    int e = tid + (k << 10);
    int lloc = e >> 6, c = e & 63;
    int gd = sl * 64 + c;
    int lseq = t0s + lloc;
    float4 wv = cwL[gd];
    float accv = cbL[gd];
    accv = fmaf(s_xz[lloc + 3][c], wv.w, accv);
    if (lseq >= 1) accv = fmaf(s_xz[lloc + 2][c], wv.z, accv);
    if (lseq >= 2) accv = fmaf(s_xz[lloc + 1][c], wv.y, accv);
    if (lseq >= 3) accv = fmaf(s_xz[lloc + 0][c], wv.x, accv);
    float sv = accv / (1.f + __expf(-accv));
    xcb[(size_t)(t0 + lloc) * 1024 + gd] = (__hip_bfloat16)sv;
    s_sv[lloc][c] = sv;
  }
  __syncthreads();
#pragma unroll
  for (int k = 0; k < 2; ++k) {
    int e = tid + (k << 10);
    int lloc = e & 31, c = e >> 5;
    int gd = sl * 64 + c;
    int token = t0 + lloc;
    xcT[(size_t)gd * 512 + token] = s_sv[lloc][c];
    zT [(size_t)gd * 512 + token] = s_xz[lloc + 3][64 + c];
  }
}

// ========== k2: selective scan + fused x_proj GEMM + dt_proj (VALU) ==========
// Each block computes its batch's dbl[256x64] itself: wave wid owns 16 token
// rows; wx staged via LDS in 8 K-tiles (aliases s_B/s_C, dead until after);
// output lands in s_cp scratch (dead until pass 2); B/C/dt extracted from LDS.
__global__ __launch_bounds__(1024) void k_scan(const __hip_bfloat16* __restrict__ xcb,
                                               const __hip_bfloat16* __restrict__ wxL,
                                               const float* __restrict__ WdtL,
                                               const float* __restrict__ bdtL,
                                               const float* __restrict__ xcT,
                                               const float* __restrict__ zT,
                                               const float* __restrict__ alog,
                                               const float* __restrict__ dv,
                                               __hip_bfloat16* __restrict__ y) {
  __shared__ __align__(16) char smem[127744];
  float (*s_dt)[LPAD] = (float(*)[LPAD])(smem);
  float (*s_xc)[LPAD] = (float(*)[LPAD])(smem + 8320);
  float (*s_B)[LPAD]  = (float(*)[LPAD])(smem + 16640);
  float (*s_C)[LPAD]  = (float(*)[LPAD])(smem + 33280);
  float (*s_cp)[68]   = (float(*)[68]) (smem + 49920);   // GEMM scratch, then partials
  float (*s_pe)[128]  = (float(*)[128])(smem + 119552);
  float (*s_se)[128]  = (float(*)[128])(smem + 123648);
  __hip_bfloat16 (*s_wx)[136] = (__hip_bfloat16(*)[136])(smem + 16640); // aliases s_B (dead)
  const int tid = threadIdx.x, bid = blockIdx.x;
  const int wid = tid >> 6, lane = tid & 63;
  const int cg = tid >> 7;
  const int tt = tid & 127;
  const int n = tt & 15, dl = tt >> 4;
  const int r = lane & 15, g = lane >> 4;
  const int b = bid >> 7;
  const int d0 = (bid & 127) << 3;
  const int d = d0 + dl;
  const int bL = b * SEQL;

  // stage xc (threads 0..511, float4 rows) — region not aliased by GEMM
  if (tid < 512) {
    int dd = tid >> 6, c4 = tid & 63;
    float4 v = *reinterpret_cast<const float4*>(xcT + (size_t)(d0 + dd) * 512 + bL + (c4 << 2));
    *reinterpret_cast<float4*>(&s_xc[dd][c4 << 2]) = v;
  }

  // ---- fused x_proj: dbl[256x64] = xcb[bL..+256][1024] * wx[64][1024]^T ----
  {
    f32x4 zz = {0.f, 0.f, 0.f, 0.f};
    f32x4 ga[4] = {zz, zz, zz, zz};
    const size_t arow = (size_t)(bL + (wid << 4) + r) * 1024;
    for (int kt = 0; kt < 8; ++kt) {
      {  // stage 64x128 wx tile (16KB)
        int row = tid >> 4, cc = tid & 15;
        *reinterpret_cast<bf16x8*>(&s_wx[row][cc << 3]) =
            *reinterpret_cast<const bf16x8*>(wxL + (size_t)row * 1024 + (kt << 7) + (cc << 3));
      }
      __syncthreads();
      const bf16x8* pa = reinterpret_cast<const bf16x8*>(xcb + arow + (kt << 7)) + g;
#pragma unroll
      for (int kc = 0; kc < 4; ++kc) {
        bf16x8 a = pa[kc * 4];
#pragma unroll
        for (int nf = 0; nf < 4; ++nf) {
          bf16x8 bf = *reinterpret_cast<const bf16x8*>(&s_wx[(nf << 4) + r][(kc << 5) + (g << 3)]);
          ga[nf] = __builtin_amdgcn_mfma_f32_16x16x32_bf16(a, bf, ga[nf], 0, 0, 0);
        }
      }
      __syncthreads();
    }
    // store dbl to scratch: row = token, col = out-channel
#pragma unroll
    for (int nf = 0; nf < 4; ++nf)
#pragma unroll
      for (int jj = 0; jj < 4; ++jj)
        s_cp[(wid << 4) + (g << 2) + jj][(nf << 4) + r] = ga[nf][jj];
  }
  __syncthreads();

  // ---- extract B/C from scratch cols 32..63 ----
#pragma unroll
  for (int k = 0; k < 4; ++k) {
    int idx = tid + (k << 10);             // 4096 = 256 x 16
    int l = idx >> 4, nn = idx & 15;
    s_B[nn][l] = s_cp[l][32 + nn];
    s_C[nn][l] = s_cp[l][48 + nn];
  }
  // ---- dt_proj + softplus from scratch cols 0..31 (f32, VALU) ----
  {
    int tk = tid >> 2, cp = (tid & 3) << 1;
    float xv[32];
    const float* drow = &s_cp[tk][0];
#pragma unroll
    for (int q = 0; q < 8; ++q) {
      float4 x4 = *reinterpret_cast<const float4*>(drow + (q << 2));
      xv[q * 4 + 0] = x4.x; xv[q * 4 + 1] = x4.y;
      xv[q * 4 + 2] = x4.z; xv[q * 4 + 3] = x4.w;
    }
#pragma unroll
    for (int kk = 0; kk < 2; ++kk) {
      int ch = cp + kk;
      const float4* wr = reinterpret_cast<const float4*>(WdtL + ((size_t)(d0 + ch) << 5));
      float acc = bdtL[d0 + ch];
#pragma unroll
      for (int q = 0; q < 8; ++q) {
        float4 w = wr[q];
        acc = fmaf(xv[q * 4 + 0], w.x, acc);
        acc = fmaf(xv[q * 4 + 1], w.y, acc);
        acc = fmaf(xv[q * 4 + 2], w.z, acc);
        acc = fmaf(xv[q * 4 + 3], w.w, acc);
      }
      s_dt[ch][tk] = (acc > 20.f) ? acc : log1pf(__expf(acc));
    }
  }
  __syncthreads();

  const float An = -__expf(alog[(size_t)d * 16 + n]);
  const int lb = cg << 5;

  // pass 1
  float s = 0.f, P = 1.f;
#pragma unroll 2
  for (int l4 = 0; l4 < CLEN; l4 += 4) {
    const int l = lb + l4;
    float4 dt4 = *reinterpret_cast<const float4*>(&s_dt[dl][l]);
    float4 xc4 = *reinterpret_cast<const float4*>(&s_xc[dl][l]);
    float4 B4  = *reinterpret_cast<const float4*>(&s_B[n][l]);
    float dA;
    dA = __expf(dt4.x * An); P *= dA; s = fmaf(dA, s, dt4.x * xc4.x * B4.x);
    dA = __expf(dt4.y * An); P *= dA; s = fmaf(dA, s, dt4.y * xc4.y * B4.y);
    dA = __expf(dt4.z * An); P *= dA; s = fmaf(dA, s, dt4.z * xc4.z * B4.z);
    dA = __expf(dt4.w * An); P *= dA; s = fmaf(dA, s, dt4.w * xc4.w * B4.w);
  }
  s_pe[cg][tt] = P;
  s_se[cg][tt] = s;
  __syncthreads();

  float ss = 0.f;
  for (int c = 0; c < cg; ++c) ss = fmaf(s_pe[c][tt], ss, s_se[c][tt]);

  // pass 2
  float s2 = ss;
#pragma unroll 2
  for (int l4 = 0; l4 < CLEN; l4 += 4) {
    const int l = lb + l4;
    float4 dt4 = *reinterpret_cast<const float4*>(&s_dt[dl][l]);
    float4 xc4 = *reinterpret_cast<const float4*>(&s_xc[dl][l]);
    float4 B4  = *reinterpret_cast<const float4*>(&s_B[n][l]);
    float4 C4  = *reinterpret_cast<const float4*>(&s_C[n][l]);
    float dA, c;
    dA = __expf(dt4.x * An); s2 = fmaf(dA, s2, dt4.x * xc4.x * B4.x); c = s2 * C4.x;
    c += __shfl_xor(c, 1); if (!(n & 1)) s_cp[l + 0][(dl << 3) | (n >> 1)] = c;
    dA = __expf(dt4.y * An); s2 = fmaf(dA, s2, dt4.y * xc4.y * B4.y); c = s2 * C4.y;
    c += __shfl_xor(c, 1); if (!(n & 1)) s_cp[l + 1][(dl << 3) | (n >> 1)] = c;
    dA = __expf(dt4.z * An); s2 = fmaf(dA, s2, dt4.z * xc4.z * B4.z); c = s2 * C4.z;
    c += __shfl_xor(c, 1); if (!(n & 1)) s_cp[l + 2][(dl << 3) | (n >> 1)] = c;
    dA = __expf(dt4.w * An); s2 = fmaf(dA, s2, dt4.w * xc4.w * B4.w); c = s2 * C4.w;
    c += __shfl_xor(c, 1); if (!(n & 1)) s_cp[l + 3][(dl << 3) | (n >> 1)] = c;
  }
  __syncthreads();

#pragma unroll
  for (int k = 0; k < 2; ++k) {
    int idx = tid + (k << 10);
    int l = idx >> 3, dd = idx & 7;
    const float* cr = &s_cp[l][dd << 3];
    float4 a0 = *reinterpret_cast<const float4*>(cr);
    float4 a1 = *reinterpret_cast<const float4*>(cr + 4);
    float sum = ((a0.x + a0.y) + (a0.z + a0.w)) + ((a1.x + a1.y) + (a1.z + a1.w));
    float xcv = s_xc[dd][l];
    float zv = zT[(size_t)(d0 + dd) * 512 + bL + l];
    float yv = (sum + dv[d0 + dd] * xcv) * (zv / (1.f + __expf(-zv)));
    y[((size_t)(bL + l) << 10) + d0 + dd] = (__hip_bfloat16)yv;
  }
}

// ========== k3: out_proj (+residual | final transposed output) ==========
template <bool FINAL>
__global__ __launch_bounds__(1024) void k_outproj(const __hip_bfloat16* __restrict__ y,
                                                  const __hip_bfloat16* __restrict__ woL,
                                                  float* __restrict__ res,
                                                  float* __restrict__ out) {
  __shared__ __align__(16) float s_red[16 * 1088 + 32 * 33];
  float (*s_tr)[33] = (float(*)[33])(s_red + 16 * 1088);
  const int tid = threadIdx.x, bid = blockIdx.x;
  const int wid = tid >> 6, lane = tid & 63;
  const int r = lane & 15, g = lane >> 4;
  int tile = bid >> 2, q = bid & 3;
  int row0 = (tile >> 3) * 64 + ((q >> 1) << 5);
  int col0 = (tile & 7) * 64 + ((q & 1) << 5);
  {
    const bf16x8* pa0 = reinterpret_cast<const bf16x8*>(y + (size_t)(row0 + r) * 1024) + g + wid * 8;
    const bf16x8* pa1 = reinterpret_cast<const bf16x8*>(y + (size_t)(row0 + 16 + r) * 1024) + g + wid * 8;
    const bf16x8* pb0 = reinterpret_cast<const bf16x8*>(woL + (size_t)(col0 + r) * 1024) + g + wid * 8;
    const bf16x8* pb1 = reinterpret_cast<const bf16x8*>(woL + (size_t)(col0 + 16 + r) * 1024) + g + wid * 8;
    f32x4 zz = {0.f, 0.f, 0.f, 0.f};
    f32x4 acc[4] = {zz, zz, zz, zz};
#pragma unroll
    for (int kc = 0; kc < 2; ++kc) {
      bf16x8 a0 = pa0[kc * 4], a1 = pa1[kc * 4];
      bf16x8 b0 = pb0[kc * 4], b1 = pb1[kc * 4];
      acc[0] = __builtin_amdgcn_mfma_f32_16x16x32_bf16(a0, b0, acc[0], 0, 0, 0);
      acc[1] = __builtin_amdgcn_mfma_f32_16x16x32_bf16(a0, b1, acc[1], 0, 0, 0);
      acc[2] = __builtin_amdgcn_mfma_f32_16x16x32_bf16(a1, b0, acc[2], 0, 0, 0);
      acc[3] = __builtin_amdgcn_mfma_f32_16x16x32_bf16(a1, b1, acc[3], 0, 0, 0);
    }
    float* sr = s_red + wid * 1088;
#pragma unroll
    for (int e = 0; e < 4; ++e)
#pragma unroll
      for (int jj = 0; jj < 4; ++jj)
        sr[(((e >> 1) << 4) + (g << 2) + jj) * 34 + ((e & 1) << 4) + r] = acc[e][jj];
  }
  __syncthreads();
  {
    int rrow = tid >> 5, rcol = tid & 31;
    float sum = 0.f;
#pragma unroll
    for (int w = 0; w < 16; ++w) sum += s_red[w * 1088 + rrow * 34 + rcol];
    if (!FINAL) {
      res[(size_t)(row0 + rrow) * 512 + col0 + rcol] += sum;
    } else {
      s_tr[rcol][rrow] = res[(size_t)(row0 + rrow) * 512 + col0 + rcol] + sum;
    }
  }
  if (FINAL) {
    __syncthreads();
    int tl = tid & 31, tc = tid >> 5;
    int b = row0 >> 8, l0 = row0 & 255;
    out[(((size_t)((b << 9) + col0 + tc)) << 8) | (l0 + tl)] = s_tr[tc][tl];
  }
}

// ---------------- launcher ----------------
extern "C" void kernel_launch(void* const* d_in, const int* in_sizes, int n_in,
                              void* d_out, int out_size, void* d_ws, size_t ws_size,
                              hipStream_t stream) {
  (void)in_sizes; (void)n_in; (void)out_size; (void)ws_size;
  const float* x    = (const float*)d_in[0];
  const float* Wi   = (const float*)d_in[1];
  const float* cw   = (const float*)d_in[2];
  const float* cb   = (const float*)d_in[3];
  const float* Wx   = (const float*)d_in[4];
  const float* Wdt  = (const float*)d_in[5];
  const float* bdt  = (const float*)d_in[6];
  const float* Alog = (const float*)d_in[7];
  const float* Dv   = (const float*)d_in[8];
  const float* Wo   = (const float*)d_in[9];
  const float* nw   = (const float*)d_in[10];

  char* ws = (char*)d_ws;
  float*          res   = (float*)(ws + 0);                  // 1 MB
  __hip_bfloat16* xcb   = (__hip_bfloat16*)(ws + 1048576);   // 1 MB
  float*          xcT   = (float*)(ws + 2097152);            // 2 MB
  float*          zT    = (float*)(ws + 4194304);            // 2 MB
  __hip_bfloat16* y     = (__hip_bfloat16*)(ws + 8454144);   // 1 MB
  __hip_bfloat16* wib   = (__hip_bfloat16*)(ws + 10485760);  // 14 MB
  __hip_bfloat16* wxb   = (__hip_bfloat16*)(ws + 25165824);  // 896 KB
  __hip_bfloat16* wob   = (__hip_bfloat16*)(ws + 26083328);  // 7 MB

  k_castin<<<NCASTB + 1024, 256, 0, stream>>>(Wi, Wx, Wo, x, wib, wxb, wob, res);

  for (int L = 0; L < NLAYER; ++L) {
    k_front<<<256, 1024, 0, stream>>>(res, nw + L * DIM,
                                      wib + (size_t)L * 2048 * 512,
                                      (const float4*)cw + (size_t)L * DINNER,
                                      cb + L * DINNER, xcb, xcT, zT);
    k_scan<<<256, 1024, 0, stream>>>(xcb, wxb + (size_t)L * 64 * 1024,
                                     Wdt + (size_t)L * DINNER * 32, bdt + L * DINNER,
                                     xcT, zT,
                                     Alog + (size_t)L * DINNER * 16, Dv + L * DINNER, y);
    if (L < NLAYER - 1)
      k_outproj<false><<<256, 1024, 0, stream>>>(y, wob + (size_t)L * 512 * 1024, res, nullptr);
    else
      k_outproj<true><<<256, 1024, 0, stream>>>(y, wob + (size_t)L * 512 * 1024, res, (float*)d_out);
  }
}

// Round 12
// 352.499 us; speedup vs baseline: 1.2101x; 1.2101x over previous
//
#include <hip/hip_runtime.h>
#include <hip/hip_bf16.h>

typedef __bf16 bf16x8 __attribute__((ext_vector_type(8)));
typedef float  f32x4  __attribute__((ext_vector_type(4)));
typedef unsigned short ushort8v __attribute__((ext_vector_type(8)));

#define DIM    512
#define DINNER 1024
#define SEQL   256
#define NLAYER 7    // layer 7's mixer output is discarded by the reference
#define LPAD   260  // [.][l] LDS row stride: 260%32==4 -> staggered banks
#define NCH    8
#define CLEN   32

#define N4WI (NLAYER * 2048 * 512 / 4)
#define N4WX (NLAYER * 64 * 1024 / 4)
#define N4WO (NLAYER * 512 * 1024 / 4)
#define N4ALL (N4WI + N4WX + N4WO)          // 2,867,200
#define NCASTB (N4ALL / 256)                // 11200 blocks

// ---------------- merged: weight casts + input transpose ----------------
__global__ __launch_bounds__(256) void k_castin(const float* __restrict__ Wi,
                                                const float* __restrict__ Wx,
                                                const float* __restrict__ Wo,
                                                const float* __restrict__ x,
                                                __hip_bfloat16* __restrict__ wib,
                                                __hip_bfloat16* __restrict__ wxb,
                                                __hip_bfloat16* __restrict__ wob,
                                                float* __restrict__ res) {
  if (blockIdx.x >= NCASTB) {   // transpose region: 1024 blocks
    int idx = (blockIdx.x - NCASTB) * 256 + threadIdx.x;   // B*L*DIM = 262144
    int d = idx & (DIM - 1), l = (idx >> 9) & (SEQL - 1), b = idx >> 17;
    res[idx] = x[((size_t)((b << 9) + d) << 8) + l];
    return;
  }
  int i = blockIdx.x * 256 + threadIdx.x;
  const float* src; __hip_bfloat16* dst; int j;
  if (i < N4WI)             { src = Wi; dst = wib; j = i; }
  else if (i < N4WI + N4WX) { src = Wx; dst = wxb; j = i - N4WI; }
  else                      { src = Wo; dst = wob; j = i - N4WI - N4WX; }
  float4 v = reinterpret_cast<const float4*>(src)[j];
  struct alignas(8) B4 { __hip_bfloat16 a, b, c, d; };
  B4 o{ (__hip_bfloat16)v.x, (__hip_bfloat16)v.y, (__hip_bfloat16)v.z, (__hip_bfloat16)v.w };
  reinterpret_cast<B4*>(dst)[j] = o;
}

// ========== k1: rmsnorm + in_proj (48x128 LDS tile) + conv + silu ==========
// (round-6/9/10 verified configuration; xcT store path removed)
__global__ __launch_bounds__(1024) void k_front(const float* __restrict__ res,
                                                const float* __restrict__ nwL,
                                                const __hip_bfloat16* __restrict__ wiL,
                                                const float4* __restrict__ cwL,
                                                const float* __restrict__ cbL,
                                                __hip_bfloat16* __restrict__ xcb,
                                                float* __restrict__ zT) {
  __shared__ __align__(16) char smem[75264];
  __hip_bfloat16 (*s_hn)[520] = (__hip_bfloat16(*)[520])smem;   // 49920B
  float (*s_xz)[132] = (float(*)[132])(smem + 49920);           // 25344B
  const int tid = threadIdx.x, bid = blockIdx.x;
  const int wid = tid >> 6, lane = tid & 63;
  const int r = lane & 15, g = lane >> 4;
  const int ttile = bid >> 4, sl = bid & 15;
  const int t0 = ttile * 32, m0 = t0 - 3;
#pragma unroll
  for (int k = 0; k < 3; ++k) {
    int rw = wid * 3 + k;
    int grc = min(max(m0 + rw, 0), 511);
    const float* rr = res + ((size_t)grc << 9);
    float v[8]; float ssum = 0.f;
#pragma unroll
    for (int j2 = 0; j2 < 8; ++j2) { v[j2] = rr[lane + (j2 << 6)]; ssum = fmaf(v[j2], v[j2], ssum); }
#pragma unroll
    for (int m = 1; m < 64; m <<= 1) ssum += __shfl_xor(ssum, m);
    float inv = rsqrtf(ssum * (1.0f / 512.0f) + 1e-5f);
#pragma unroll
    for (int j2 = 0; j2 < 8; ++j2)
      s_hn[rw][lane + (j2 << 6)] = (__hip_bfloat16)(v[j2] * inv * nwL[lane + (j2 << 6)]);
  }
  __syncthreads();
  for (int j = wid; j < 24; j += 16) {
    int mf = j >> 3, cf = j & 7;
    int gcol = (cf < 4) ? (sl * 64 + cf * 16 + r) : (1024 + sl * 64 + (cf - 4) * 16 + r);
    const bf16x8* pb = reinterpret_cast<const bf16x8*>(wiL + (size_t)gcol * 512) + g;
    f32x4 acc = {0.f, 0.f, 0.f, 0.f};
#pragma unroll
    for (int kc = 0; kc < 16; ++kc) {
      bf16x8 a = *reinterpret_cast<const bf16x8*>(&s_hn[mf * 16 + r][kc * 32 + g * 8]);
      acc = __builtin_amdgcn_mfma_f32_16x16x32_bf16(a, pb[kc * 4], acc, 0, 0, 0);
    }
    int cc = (cf < 4) ? (cf * 16 + r) : (64 + (cf - 4) * 16 + r);
#pragma unroll
    for (int jj = 0; jj < 4; ++jj) s_xz[mf * 16 + g * 4 + jj][cc] = acc[jj];
  }
  __syncthreads();
  const int t0s = t0 & 255;
#pragma unroll
  for (int k = 0; k < 2; ++k) {
    int e = tid + (k << 10);
    int lloc = e >> 6, c = e & 63;
    int gd = sl * 64 + c;
    int lseq = t0s + lloc;
    float4 wv = cwL[gd];
    float accv = cbL[gd];
    accv = fmaf(s_xz[lloc + 3][c], wv.w, accv);
    if (lseq >= 1) accv = fmaf(s_xz[lloc + 2][c], wv.z, accv);
    if (lseq >= 2) accv = fmaf(s_xz[lloc + 1][c], wv.y, accv);
    if (lseq >= 3) accv = fmaf(s_xz[lloc + 0][c], wv.x, accv);
    float sv = accv / (1.f + __expf(-accv));
    xcb[(size_t)(t0 + lloc) * 1024 + gd] = (__hip_bfloat16)sv;
  }
  __syncthreads();
  // transposed z stores (coalesced over tokens)
#pragma unroll
  for (int k = 0; k < 2; ++k) {
    int e = tid + (k << 10);
    int lloc = e & 31, c = e >> 5;
    int gd = sl * 64 + c;
    zT[(size_t)gd * 512 + t0 + lloc] = s_xz[lloc + 3][64 + c];
  }
}

// ========== k2: x_proj (4-way split-K); outputs B/C f32 + dtr bf16 ==========
__global__ __launch_bounds__(1024) void k_xdt(const __hip_bfloat16* __restrict__ xcb,
                                              const __hip_bfloat16* __restrict__ wxL,
                                              float* __restrict__ dblBC,
                                              __hip_bfloat16* __restrict__ dtrb) {
  __shared__ __align__(16) float s_red[4 * 1088];   // 17408B
  const int tid = threadIdx.x, bid = blockIdx.x;
  const int wid = tid >> 6, lane = tid & 63;
  const int r = lane & 15, g = lane >> 4;
  const int t0 = bid * 16;
  {
    int nf = wid >> 2, ks = wid & 3;
    const bf16x8* pa = reinterpret_cast<const bf16x8*>(xcb + (size_t)(t0 + r) * 1024) + ks * 32 + g;
    const bf16x8* pb = reinterpret_cast<const bf16x8*>(wxL + (size_t)(nf * 16 + r) * 1024) + ks * 32 + g;
    f32x4 acc = {0.f, 0.f, 0.f, 0.f};
#pragma unroll
    for (int kc = 0; kc < 8; ++kc)
      acc = __builtin_amdgcn_mfma_f32_16x16x32_bf16(pa[kc * 4], pb[kc * 4], acc, 0, 0, 0);
#pragma unroll
    for (int jj = 0; jj < 4; ++jj)
      s_red[ks * 1088 + (g * 4 + jj) * 68 + nf * 16 + r] = acc[jj];
  }
  __syncthreads();
  {
    int row = tid >> 6, col = tid & 63;
    float dsum = s_red[row * 68 + col] + s_red[1088 + row * 68 + col]
               + s_red[2176 + row * 68 + col] + s_red[3264 + row * 68 + col];
    if (col >= 32) dblBC[((size_t)(t0 + row) << 5) + (col - 32)] = dsum;
    else           dtrb [((size_t)(t0 + row) << 5) + col] = (__hip_bfloat16)dsum;
  }
}

// ========== k3: selective scan v4 + fused dt_proj (VALU); xc from xcb ==========
__global__ __launch_bounds__(1024) void k_scan(const float* __restrict__ dblBC,
                                               const __hip_bfloat16* __restrict__ dtrb,
                                               const float* __restrict__ WdtL,
                                               const float* __restrict__ bdtL,
                                               const __hip_bfloat16* __restrict__ xcb,
                                               const float* __restrict__ zT,
                                               const float* __restrict__ alog,
                                               const float* __restrict__ dv,
                                               __hip_bfloat16* __restrict__ y) {
  __shared__ __align__(16) char smem[127744];
  float (*s_dt)[LPAD] = (float(*)[LPAD])(smem);
  float (*s_xc)[LPAD] = (float(*)[LPAD])(smem + 8320);
  float (*s_B)[LPAD]  = (float(*)[LPAD])(smem + 16640);
  float (*s_C)[LPAD]  = (float(*)[LPAD])(smem + 33280);
  float (*s_cp)[68]   = (float(*)[68]) (smem + 49920);
  float (*s_pe)[128]  = (float(*)[128])(smem + 119552);
  float (*s_se)[128]  = (float(*)[128])(smem + 123648);
  const int tid = threadIdx.x, bid = blockIdx.x;
  const int cg = tid >> 7;
  const int tt = tid & 127;
  const int n = tt & 15, dl = tt >> 4;
  const int b = bid >> 7;
  const int d0 = (bid & 127) << 3;
  const int d = d0 + dl;
  const int bL = b * SEQL;

  // stage B,C from dblBC (2 float4 per thread, coalesced)
#pragma unroll
  for (int k = 0; k < 2; ++k) {
    int fidx = tid + (k << 10);
    int l = fidx >> 3, q = fidx & 7;
    float4 v = *reinterpret_cast<const float4*>(dblBC + ((size_t)(bL + l) << 5) + (q << 2));
    float* dst = (q < 4) ? &s_B[(q & 3) << 2][l] : &s_C[(q & 3) << 2][l];
    dst[0] = v.x; dst[LPAD] = v.y; dst[2 * LPAD] = v.z; dst[3 * LPAD] = v.w;
  }
  // stage xc straight from xcb (bf16, L2-resident): 1 token x 8 ch per thread
  if (tid < 256) {
    bf16x8 u = *reinterpret_cast<const bf16x8*>(xcb + (size_t)(bL + tid) * 1024 + d0);
#pragma unroll
    for (int e = 0; e < 8; ++e) s_xc[e][tid] = (float)u[e];
  }
  // fused dt_proj + softplus: each thread does 1 token x 2 channels (VALU)
  {
    int tk = tid >> 2;                    // token 0..255
    int cp = (tid & 3) << 1;              // channel pair 0,2,4,6
    const ushort8v* drp = reinterpret_cast<const ushort8v*>(
        reinterpret_cast<const unsigned short*>(dtrb) + ((size_t)(bL + tk) << 5));
    float xv[32];
#pragma unroll
    for (int q = 0; q < 4; ++q) {
      ushort8v u = drp[q];
#pragma unroll
      for (int e = 0; e < 8; ++e)
        xv[q * 8 + e] = __uint_as_float(((unsigned int)u[e]) << 16);
    }
#pragma unroll
    for (int kk = 0; kk < 2; ++kk) {
      int ch = cp + kk;
      const float4* wr = reinterpret_cast<const float4*>(WdtL + ((size_t)(d0 + ch) << 5));
      float acc = bdtL[d0 + ch];
#pragma unroll
      for (int q = 0; q < 8; ++q) {
        float4 w = wr[q];
        acc = fmaf(xv[q * 4 + 0], w.x, acc);
        acc = fmaf(xv[q * 4 + 1], w.y, acc);
        acc = fmaf(xv[q * 4 + 2], w.z, acc);
        acc = fmaf(xv[q * 4 + 3], w.w, acc);
      }
      s_dt[ch][tk] = (acc > 20.f) ? acc : log1pf(__expf(acc));
    }
  }
  __syncthreads();

  const float An = -__expf(alog[(size_t)d * 16 + n]);
  const int lb = cg << 5;

  // pass 1
  float s = 0.f, P = 1.f;
#pragma unroll 2
  for (int l4 = 0; l4 < CLEN; l4 += 4) {
    const int l = lb + l4;
    float4 dt4 = *reinterpret_cast<const float4*>(&s_dt[dl][l]);
    float4 xc4 = *reinterpret_cast<const float4*>(&s_xc[dl][l]);
    float4 B4  = *reinterpret_cast<const float4*>(&s_B[n][l]);
    float dA;
    dA = __expf(dt4.x * An); P *= dA; s = fmaf(dA, s, dt4.x * xc4.x * B4.x);
    dA = __expf(dt4.y * An); P *= dA; s = fmaf(dA, s, dt4.y * xc4.y * B4.y);
    dA = __expf(dt4.z * An); P *= dA; s = fmaf(dA, s, dt4.z * xc4.z * B4.z);
    dA = __expf(dt4.w * An); P *= dA; s = fmaf(dA, s, dt4.w * xc4.w * B4.w);
  }
  s_pe[cg][tt] = P;
  s_se[cg][tt] = s;
  __syncthreads();

  float ss = 0.f;
  for (int c = 0; c < cg; ++c) ss = fmaf(s_pe[c][tt], ss, s_se[c][tt]);

  // pass 2
  float s2 = ss;
#pragma unroll 2
  for (int l4 = 0; l4 < CLEN; l4 += 4) {
    const int l = lb + l4;
    float4 dt4 = *reinterpret_cast<const float4*>(&s_dt[dl][l]);
    float4 xc4 = *reinterpret_cast<const float4*>(&s_xc[dl][l]);
    float4 B4  = *reinterpret_cast<const float4*>(&s_B[n][l]);
    float4 C4  = *reinterpret_cast<const float4*>(&s_C[n][l]);
    float dA, c;
    dA = __expf(dt4.x * An); s2 = fmaf(dA, s2, dt4.x * xc4.x * B4.x); c = s2 * C4.x;
    c += __shfl_xor(c, 1); if (!(n & 1)) s_cp[l + 0][(dl << 3) | (n >> 1)] = c;
    dA = __expf(dt4.y * An); s2 = fmaf(dA, s2, dt4.y * xc4.y * B4.y); c = s2 * C4.y;
    c += __shfl_xor(c, 1); if (!(n & 1)) s_cp[l + 1][(dl << 3) | (n >> 1)] = c;
    dA = __expf(dt4.z * An); s2 = fmaf(dA, s2, dt4.z * xc4.z * B4.z); c = s2 * C4.z;
    c += __shfl_xor(c, 1); if (!(n & 1)) s_cp[l + 2][(dl << 3) | (n >> 1)] = c;
    dA = __expf(dt4.w * An); s2 = fmaf(dA, s2, dt4.w * xc4.w * B4.w); c = s2 * C4.w;
    c += __shfl_xor(c, 1); if (!(n & 1)) s_cp[l + 3][(dl << 3) | (n >> 1)] = c;
  }
  __syncthreads();

#pragma unroll
  for (int k = 0; k < 2; ++k) {
    int idx = tid + (k << 10);
    int l = idx >> 3, dd = idx & 7;
    const float* cr = &s_cp[l][dd << 3];
    float4 a0 = *reinterpret_cast<const float4*>(cr);
    float4 a1 = *reinterpret_cast<const float4*>(cr + 4);
    float sum = ((a0.x + a0.y) + (a0.z + a0.w)) + ((a1.x + a1.y) + (a1.z + a1.w));
    float xcv = s_xc[dd][l];
    float zv = zT[(size_t)(d0 + dd) * 512 + bL + l];
    float yv = (sum + dv[d0 + dd] * xcv) * (zv / (1.f + __expf(-zv)));
    y[((size_t)(bL + l) << 10) + d0 + dd] = (__hip_bfloat16)yv;
  }
}

// ========== k4: out_proj (+residual | final transposed output) ==========
template <bool FINAL>
__global__ __launch_bounds__(1024) void k_outproj(const __hip_bfloat16* __restrict__ y,
                                                  const __hip_bfloat16* __restrict__ woL,
                                                  float* __restrict__ res,
                                                  float* __restrict__ out) {
  __shared__ __align__(16) float s_red[16 * 1088 + 32 * 33];
  float (*s_tr)[33] = (float(*)[33])(s_red + 16 * 1088);
  const int tid = threadIdx.x, bid = blockIdx.x;
  const int wid = tid >> 6, lane = tid & 63;
  const int r = lane & 15, g = lane >> 4;
  int tile = bid >> 2, q = bid & 3;
  int row0 = (tile >> 3) * 64 + ((q >> 1) << 5);
  int col0 = (tile & 7) * 64 + ((q & 1) << 5);
  {
    const bf16x8* pa0 = reinterpret_cast<const bf16x8*>(y + (size_t)(row0 + r) * 1024) + g + wid * 8;
    const bf16x8* pa1 = reinterpret_cast<const bf16x8*>(y + (size_t)(row0 + 16 + r) * 1024) + g + wid * 8;
    const bf16x8* pb0 = reinterpret_cast<const bf16x8*>(woL + (size_t)(col0 + r) * 1024) + g + wid * 8;
    const bf16x8* pb1 = reinterpret_cast<const bf16x8*>(woL + (size_t)(col0 + 16 + r) * 1024) + g + wid * 8;
    f32x4 zz = {0.f, 0.f, 0.f, 0.f};
    f32x4 acc[4] = {zz, zz, zz, zz};
#pragma unroll
    for (int kc = 0; kc < 2; ++kc) {
      bf16x8 a0 = pa0[kc * 4], a1 = pa1[kc * 4];
      bf16x8 b0 = pb0[kc * 4], b1 = pb1[kc * 4];
      acc[0] = __builtin_amdgcn_mfma_f32_16x16x32_bf16(a0, b0, acc[0], 0, 0, 0);
      acc[1] = __builtin_amdgcn_mfma_f32_16x16x32_bf16(a0, b1, acc[1], 0, 0, 0);
      acc[2] = __builtin_amdgcn_mfma_f32_16x16x32_bf16(a1, b0, acc[2], 0, 0, 0);
      acc[3] = __builtin_amdgcn_mfma_f32_16x16x32_bf16(a1, b1, acc[3], 0, 0, 0);
    }
    float* sr = s_red + wid * 1088;
#pragma unroll
    for (int e = 0; e < 4; ++e)
#pragma unroll
      for (int jj = 0; jj < 4; ++jj)
        sr[(((e >> 1) << 4) + (g << 2) + jj) * 34 + ((e & 1) << 4) + r] = acc[e][jj];
  }
  __syncthreads();
  {
    int rrow = tid >> 5, rcol = tid & 31;
    float sum = 0.f;
#pragma unroll
    for (int w = 0; w < 16; ++w) sum += s_red[w * 1088 + rrow * 34 + rcol];
    if (!FINAL) {
      res[(size_t)(row0 + rrow) * 512 + col0 + rcol] += sum;
    } else {
      s_tr[rcol][rrow] = res[(size_t)(row0 + rrow) * 512 + col0 + rcol] + sum;
    }
  }
  if (FINAL) {
    __syncthreads();
    int tl = tid & 31, tc = tid >> 5;
    int b = row0 >> 8, l0 = row0 & 255;
    out[(((size_t)((b << 9) + col0 + tc)) << 8) | (l0 + tl)] = s_tr[tc][tl];
  }
}

// ---------------- launcher ----------------
extern "C" void kernel_launch(void* const* d_in, const int* in_sizes, int n_in,
                              void* d_out, int out_size, void* d_ws, size_t ws_size,
                              hipStream_t stream) {
  (void)in_sizes; (void)n_in; (void)out_size; (void)ws_size;
  const float* x    = (const float*)d_in[0];
  const float* Wi   = (const float*)d_in[1];
  const float* cw   = (const float*)d_in[2];
  const float* cb   = (const float*)d_in[3];
  const float* Wx   = (const float*)d_in[4];
  const float* Wdt  = (const float*)d_in[5];
  const float* bdt  = (const float*)d_in[6];
  const float* Alog = (const float*)d_in[7];
  const float* Dv   = (const float*)d_in[8];
  const float* Wo   = (const float*)d_in[9];
  const float* nw   = (const float*)d_in[10];

  char* ws = (char*)d_ws;
  float*          res   = (float*)(ws + 0);                  // 1 MB
  __hip_bfloat16* xcb   = (__hip_bfloat16*)(ws + 1048576);   // 1 MB
  float*          zT    = (float*)(ws + 4194304);            // 2 MB
  __hip_bfloat16* dtrb  = (__hip_bfloat16*)(ws + 6291456);   // 32 KB
  float*          dblBC = (float*)(ws + 8388608);            // 64 KB
  __hip_bfloat16* y     = (__hip_bfloat16*)(ws + 8454144);   // 1 MB
  __hip_bfloat16* wib   = (__hip_bfloat16*)(ws + 10485760);  // 14 MB
  __hip_bfloat16* wxb   = (__hip_bfloat16*)(ws + 25165824);  // 896 KB
  __hip_bfloat16* wob   = (__hip_bfloat16*)(ws + 26083328);  // 7 MB

  k_castin<<<NCASTB + 1024, 256, 0, stream>>>(Wi, Wx, Wo, x, wib, wxb, wob, res);

  for (int L = 0; L < NLAYER; ++L) {
    k_front<<<256, 1024, 0, stream>>>(res, nw + L * DIM,
                                      wib + (size_t)L * 2048 * 512,
                                      (const float4*)cw + (size_t)L * DINNER,
                                      cb + L * DINNER, xcb, zT);
    k_xdt<<<32, 1024, 0, stream>>>(xcb, wxb + (size_t)L * 64 * 1024, dblBC, dtrb);
    k_scan<<<256, 1024, 0, stream>>>(dblBC, dtrb,
                                     Wdt + (size_t)L * DINNER * 32, bdt + L * DINNER,
                                     xcb, zT,
                                     Alog + (size_t)L * DINNER * 16, Dv + L * DINNER, y);
    if (L < NLAYER - 1)
      k_outproj<false><<<256, 1024, 0, stream>>>(y, wob + (size_t)L * 512 * 1024, res, nullptr);
    else
      k_outproj<true><<<256, 1024, 0, stream>>>(y, wob + (size_t)L * 512 * 1024, res, (float*)d_out);
  }
}

// Round 13
// 306.500 us; speedup vs baseline: 1.3917x; 1.1501x over previous
//
#include <hip/hip_runtime.h>
#include <hip/hip_bf16.h>

typedef __bf16 bf16x8 __attribute__((ext_vector_type(8)));
typedef float  f32x4  __attribute__((ext_vector_type(4)));

#define DIM    512
#define DINNER 1024
#define SEQL   256
#define NLAYER 7    // layer 7's mixer output is discarded by the reference
#define LPAD   260  // [.][l] LDS row stride: 260%32==4 -> staggered banks
#define NCH    8
#define CLEN   32

#define N4WI (NLAYER * 2048 * 512 / 4)
#define N4WX (NLAYER * 64 * 1024 / 4)
#define N4WO (NLAYER * 512 * 1024 / 4)
#define N4ALL (N4WI + N4WX + N4WO)          // 2,867,200
#define NCASTB (N4ALL / 256)                // 11200 blocks

// ---------------- merged: weight casts + input transpose + dblraw zero ----------
__global__ __launch_bounds__(256) void k_castin(const float* __restrict__ Wi,
                                                const float* __restrict__ Wx,
                                                const float* __restrict__ Wo,
                                                const float* __restrict__ x,
                                                __hip_bfloat16* __restrict__ wib,
                                                __hip_bfloat16* __restrict__ wxb,
                                                __hip_bfloat16* __restrict__ wob,
                                                float* __restrict__ res,
                                                float* __restrict__ dblraw) {
  if (blockIdx.x >= NCASTB + 1024) {  // zero dblraw[512][64]: 8192 float4, 32 blocks
    int i = (blockIdx.x - NCASTB - 1024) * 256 + threadIdx.x;
    reinterpret_cast<float4*>(dblraw)[i] = float4{0.f, 0.f, 0.f, 0.f};
    return;
  }
  if (blockIdx.x >= NCASTB) {   // transpose region: 1024 blocks
    int idx = (blockIdx.x - NCASTB) * 256 + threadIdx.x;   // B*L*DIM = 262144
    int d = idx & (DIM - 1), l = (idx >> 9) & (SEQL - 1), b = idx >> 17;
    res[idx] = x[((size_t)((b << 9) + d) << 8) + l];
    return;
  }
  int i = blockIdx.x * 256 + threadIdx.x;
  const float* src; __hip_bfloat16* dst; int j;
  if (i < N4WI)             { src = Wi; dst = wib; j = i; }
  else if (i < N4WI + N4WX) { src = Wx; dst = wxb; j = i - N4WI; }
  else                      { src = Wo; dst = wob; j = i - N4WI - N4WX; }
  float4 v = reinterpret_cast<const float4*>(src)[j];
  struct alignas(8) B4 { __hip_bfloat16 a, b, c, d; };
  B4 o{ (__hip_bfloat16)v.x, (__hip_bfloat16)v.y, (__hip_bfloat16)v.z, (__hip_bfloat16)v.w };
  reinterpret_cast<B4*>(dst)[j] = o;
}

// ========== k1: rmsnorm + in_proj + conv + silu + partial x_proj (atomics) ======
// r6/9/10-verified body; new final phase: waves 0..7 compute this block's K-slice
// of x_proj (xc[32tok x 64ch] * wx[64out x 64ch]^T) and atomicAdd into
// dblraw[512][64] (device-scope; atomics = cross-block K-reduction).
__global__ __launch_bounds__(1024) void k_front(const float* __restrict__ res,
                                                const float* __restrict__ nwL,
                                                const __hip_bfloat16* __restrict__ wiL,
                                                const __hip_bfloat16* __restrict__ wxL,
                                                const float4* __restrict__ cwL,
                                                const float* __restrict__ cbL,
                                                __hip_bfloat16* __restrict__ xcb,
                                                float* __restrict__ zT,
                                                float* __restrict__ dblraw) {
  __shared__ __align__(16) char smem[79872];
  __hip_bfloat16 (*s_hn)[520] = (__hip_bfloat16(*)[520])smem;   // 49920B
  float (*s_xz)[132] = (float(*)[132])(smem + 49920);           // 25344B
  __hip_bfloat16 (*s_xcb)[72] = (__hip_bfloat16(*)[72])(smem + 75264); // 4608B
  const int tid = threadIdx.x, bid = blockIdx.x;
  const int wid = tid >> 6, lane = tid & 63;
  const int r = lane & 15, g = lane >> 4;
  const int ttile = bid >> 4, sl = bid & 15;
  const int t0 = ttile * 32, m0 = t0 - 3;
#pragma unroll
  for (int k = 0; k < 3; ++k) {
    int rw = wid * 3 + k;
    int grc = min(max(m0 + rw, 0), 511);
    const float* rr = res + ((size_t)grc << 9);
    float v[8]; float ssum = 0.f;
#pragma unroll
    for (int j2 = 0; j2 < 8; ++j2) { v[j2] = rr[lane + (j2 << 6)]; ssum = fmaf(v[j2], v[j2], ssum); }
#pragma unroll
    for (int m = 1; m < 64; m <<= 1) ssum += __shfl_xor(ssum, m);
    float inv = rsqrtf(ssum * (1.0f / 512.0f) + 1e-5f);
#pragma unroll
    for (int j2 = 0; j2 < 8; ++j2)
      s_hn[rw][lane + (j2 << 6)] = (__hip_bfloat16)(v[j2] * inv * nwL[lane + (j2 << 6)]);
  }
  __syncthreads();
  for (int j = wid; j < 24; j += 16) {
    int mf = j >> 3, cf = j & 7;
    int gcol = (cf < 4) ? (sl * 64 + cf * 16 + r) : (1024 + sl * 64 + (cf - 4) * 16 + r);
    const bf16x8* pb = reinterpret_cast<const bf16x8*>(wiL + (size_t)gcol * 512) + g;
    f32x4 acc = {0.f, 0.f, 0.f, 0.f};
#pragma unroll
    for (int kc = 0; kc < 16; ++kc) {
      bf16x8 a = *reinterpret_cast<const bf16x8*>(&s_hn[mf * 16 + r][kc * 32 + g * 8]);
      acc = __builtin_amdgcn_mfma_f32_16x16x32_bf16(a, pb[kc * 4], acc, 0, 0, 0);
    }
    int cc = (cf < 4) ? (cf * 16 + r) : (64 + (cf - 4) * 16 + r);
#pragma unroll
    for (int jj = 0; jj < 4; ++jj) s_xz[mf * 16 + g * 4 + jj][cc] = acc[jj];
  }
  __syncthreads();
  const int t0s = t0 & 255;
#pragma unroll
  for (int k = 0; k < 2; ++k) {
    int e = tid + (k << 10);
    int lloc = e >> 6, c = e & 63;
    int gd = sl * 64 + c;
    int lseq = t0s + lloc;
    float4 wv = cwL[gd];
    float accv = cbL[gd];
    accv = fmaf(s_xz[lloc + 3][c], wv.w, accv);
    if (lseq >= 1) accv = fmaf(s_xz[lloc + 2][c], wv.z, accv);
    if (lseq >= 2) accv = fmaf(s_xz[lloc + 1][c], wv.y, accv);
    if (lseq >= 3) accv = fmaf(s_xz[lloc + 0][c], wv.x, accv);
    float sv = accv / (1.f + __expf(-accv));
    __hip_bfloat16 hb = (__hip_bfloat16)sv;
    xcb[(size_t)(t0 + lloc) * 1024 + gd] = hb;
    s_xcb[lloc][c] = hb;
  }
  __syncthreads();
  if (wid < 8) {
    // partial x_proj: jobs (mf 0/1 token-frag, nf 0..3 out-frag), K=64
    int mf = wid & 1, nf = wid >> 1;
    f32x4 acc = {0.f, 0.f, 0.f, 0.f};
#pragma unroll
    for (int kc = 0; kc < 2; ++kc) {
      bf16x8 a = *reinterpret_cast<const bf16x8*>(&s_xcb[mf * 16 + r][kc * 32 + g * 8]);
      bf16x8 bb = *reinterpret_cast<const bf16x8*>(
          wxL + (size_t)(nf * 16 + r) * 1024 + sl * 64 + kc * 32 + g * 8);
      acc = __builtin_amdgcn_mfma_f32_16x16x32_bf16(a, bb, acc, 0, 0, 0);
    }
#pragma unroll
    for (int jj = 0; jj < 4; ++jj)
      atomicAdd(&dblraw[(size_t)(t0 + mf * 16 + g * 4 + jj) * 64 + nf * 16 + r], acc[jj]);
  } else {
    // transposed z stores (512 threads x 4)
#pragma unroll
    for (int k = 0; k < 4; ++k) {
      int e = (tid - 512) + (k << 9);      // 2048 = 32 tok x 64 ch
      int lloc = e & 31, c = e >> 5;
      int gd = sl * 64 + c;
      zT[(size_t)gd * 512 + t0 + lloc] = s_xz[lloc + 3][64 + c];
    }
  }
}

// ========== k2: selective scan v4 + dt_proj (f32, VALU); inputs from dblraw =====
__global__ __launch_bounds__(1024) void k_scan(const float* __restrict__ dblraw,
                                               const float* __restrict__ WdtL,
                                               const float* __restrict__ bdtL,
                                               const __hip_bfloat16* __restrict__ xcb,
                                               const float* __restrict__ zT,
                                               const float* __restrict__ alog,
                                               const float* __restrict__ dv,
                                               __hip_bfloat16* __restrict__ y) {
  __shared__ __align__(16) char smem[127744];
  float (*s_dt)[LPAD] = (float(*)[LPAD])(smem);
  float (*s_xc)[LPAD] = (float(*)[LPAD])(smem + 8320);
  float (*s_B)[LPAD]  = (float(*)[LPAD])(smem + 16640);
  float (*s_C)[LPAD]  = (float(*)[LPAD])(smem + 33280);
  float (*s_cp)[68]   = (float(*)[68]) (smem + 49920);
  float (*s_pe)[128]  = (float(*)[128])(smem + 119552);
  float (*s_se)[128]  = (float(*)[128])(smem + 123648);
  const int tid = threadIdx.x, bid = blockIdx.x;
  const int cg = tid >> 7;
  const int tt = tid & 127;
  const int n = tt & 15, dl = tt >> 4;
  const int b = bid >> 7;
  const int d0 = (bid & 127) << 3;
  const int d = d0 + dl;
  const int bL = b * SEQL;

  // stage B,C from dblraw cols 32..63 (2 float4 per thread, coalesced)
#pragma unroll
  for (int k = 0; k < 2; ++k) {
    int fidx = tid + (k << 10);
    int l = fidx >> 3, q = fidx & 7;
    float4 v = *reinterpret_cast<const float4*>(dblraw + ((size_t)(bL + l) << 6) + 32 + (q << 2));
    float* dst = (q < 4) ? &s_B[(q & 3) << 2][l] : &s_C[(q & 3) << 2][l];
    dst[0] = v.x; dst[LPAD] = v.y; dst[2 * LPAD] = v.z; dst[3 * LPAD] = v.w;
  }
  // stage xc straight from xcb (bf16, L2-resident): 1 token x 8 ch per thread
  if (tid < 256) {
    bf16x8 u = *reinterpret_cast<const bf16x8*>(xcb + (size_t)(bL + tid) * 1024 + d0);
#pragma unroll
    for (int e = 0; e < 8; ++e) s_xc[e][tid] = (float)u[e];
  }
  // fused dt_proj + softplus from dblraw cols 0..31 (f32, VALU)
  {
    int tk = tid >> 2;                    // token 0..255
    int cp = (tid & 3) << 1;              // channel pair 0,2,4,6
    const float* drow = dblraw + ((size_t)(bL + tk) << 6);
    float xv[32];
#pragma unroll
    for (int q = 0; q < 8; ++q) {
      float4 x4 = *reinterpret_cast<const float4*>(drow + (q << 2));
      xv[q * 4 + 0] = x4.x; xv[q * 4 + 1] = x4.y;
      xv[q * 4 + 2] = x4.z; xv[q * 4 + 3] = x4.w;
    }
#pragma unroll
    for (int kk = 0; kk < 2; ++kk) {
      int ch = cp + kk;
      const float4* wr = reinterpret_cast<const float4*>(WdtL + ((size_t)(d0 + ch) << 5));
      float acc = bdtL[d0 + ch];
#pragma unroll
      for (int q = 0; q < 8; ++q) {
        float4 w = wr[q];
        acc = fmaf(xv[q * 4 + 0], w.x, acc);
        acc = fmaf(xv[q * 4 + 1], w.y, acc);
        acc = fmaf(xv[q * 4 + 2], w.z, acc);
        acc = fmaf(xv[q * 4 + 3], w.w, acc);
      }
      s_dt[ch][tk] = (acc > 20.f) ? acc : log1pf(__expf(acc));
    }
  }
  __syncthreads();

  const float An = -__expf(alog[(size_t)d * 16 + n]);
  const int lb = cg << 5;

  // pass 1
  float s = 0.f, P = 1.f;
#pragma unroll 2
  for (int l4 = 0; l4 < CLEN; l4 += 4) {
    const int l = lb + l4;
    float4 dt4 = *reinterpret_cast<const float4*>(&s_dt[dl][l]);
    float4 xc4 = *reinterpret_cast<const float4*>(&s_xc[dl][l]);
    float4 B4  = *reinterpret_cast<const float4*>(&s_B[n][l]);
    float dA;
    dA = __expf(dt4.x * An); P *= dA; s = fmaf(dA, s, dt4.x * xc4.x * B4.x);
    dA = __expf(dt4.y * An); P *= dA; s = fmaf(dA, s, dt4.y * xc4.y * B4.y);
    dA = __expf(dt4.z * An); P *= dA; s = fmaf(dA, s, dt4.z * xc4.z * B4.z);
    dA = __expf(dt4.w * An); P *= dA; s = fmaf(dA, s, dt4.w * xc4.w * B4.w);
  }
  s_pe[cg][tt] = P;
  s_se[cg][tt] = s;
  __syncthreads();

  float ss = 0.f;
  for (int c = 0; c < cg; ++c) ss = fmaf(s_pe[c][tt], ss, s_se[c][tt]);

  // pass 2
  float s2 = ss;
#pragma unroll 2
  for (int l4 = 0; l4 < CLEN; l4 += 4) {
    const int l = lb + l4;
    float4 dt4 = *reinterpret_cast<const float4*>(&s_dt[dl][l]);
    float4 xc4 = *reinterpret_cast<const float4*>(&s_xc[dl][l]);
    float4 B4  = *reinterpret_cast<const float4*>(&s_B[n][l]);
    float4 C4  = *reinterpret_cast<const float4*>(&s_C[n][l]);
    float dA, c;
    dA = __expf(dt4.x * An); s2 = fmaf(dA, s2, dt4.x * xc4.x * B4.x); c = s2 * C4.x;
    c += __shfl_xor(c, 1); if (!(n & 1)) s_cp[l + 0][(dl << 3) | (n >> 1)] = c;
    dA = __expf(dt4.y * An); s2 = fmaf(dA, s2, dt4.y * xc4.y * B4.y); c = s2 * C4.y;
    c += __shfl_xor(c, 1); if (!(n & 1)) s_cp[l + 1][(dl << 3) | (n >> 1)] = c;
    dA = __expf(dt4.z * An); s2 = fmaf(dA, s2, dt4.z * xc4.z * B4.z); c = s2 * C4.z;
    c += __shfl_xor(c, 1); if (!(n & 1)) s_cp[l + 2][(dl << 3) | (n >> 1)] = c;
    dA = __expf(dt4.w * An); s2 = fmaf(dA, s2, dt4.w * xc4.w * B4.w); c = s2 * C4.w;
    c += __shfl_xor(c, 1); if (!(n & 1)) s_cp[l + 3][(dl << 3) | (n >> 1)] = c;
  }
  __syncthreads();

#pragma unroll
  for (int k = 0; k < 2; ++k) {
    int idx = tid + (k << 10);
    int l = idx >> 3, dd = idx & 7;
    const float* cr = &s_cp[l][dd << 3];
    float4 a0 = *reinterpret_cast<const float4*>(cr);
    float4 a1 = *reinterpret_cast<const float4*>(cr + 4);
    float sum = ((a0.x + a0.y) + (a0.z + a0.w)) + ((a1.x + a1.y) + (a1.z + a1.w));
    float xcv = s_xc[dd][l];
    float zv = zT[(size_t)(d0 + dd) * 512 + bL + l];
    float yv = (sum + dv[d0 + dd] * xcv) * (zv / (1.f + __expf(-zv)));
    y[((size_t)(bL + l) << 10) + d0 + dd] = (__hip_bfloat16)yv;
  }
}

// ========== k3: out_proj (+residual | final transposed out) + dblraw zeroing ====
template <bool FINAL>
__global__ __launch_bounds__(1024) void k_outproj(const __hip_bfloat16* __restrict__ y,
                                                  const __hip_bfloat16* __restrict__ woL,
                                                  float* __restrict__ res,
                                                  float* __restrict__ out,
                                                  float* __restrict__ dblraw) {
  __shared__ __align__(16) float s_red[16 * 1088 + 32 * 33];
  float (*s_tr)[33] = (float(*)[33])(s_red + 16 * 1088);
  const int tid = threadIdx.x, bid = blockIdx.x;
  const int wid = tid >> 6, lane = tid & 63;
  const int r = lane & 15, g = lane >> 4;
  int tile = bid >> 2, q = bid & 3;
  int row0 = (tile >> 3) * 64 + ((q >> 1) << 5);
  int col0 = (tile & 7) * 64 + ((q & 1) << 5);
  // zero dblraw for next layer's k_front atomics (scan has already read it)
  if (!FINAL && tid < 32)
    reinterpret_cast<float4*>(dblraw)[bid * 32 + tid] = float4{0.f, 0.f, 0.f, 0.f};
  {
    const bf16x8* pa0 = reinterpret_cast<const bf16x8*>(y + (size_t)(row0 + r) * 1024) + g + wid * 8;
    const bf16x8* pa1 = reinterpret_cast<const bf16x8*>(y + (size_t)(row0 + 16 + r) * 1024) + g + wid * 8;
    const bf16x8* pb0 = reinterpret_cast<const bf16x8*>(woL + (size_t)(col0 + r) * 1024) + g + wid * 8;
    const bf16x8* pb1 = reinterpret_cast<const bf16x8*>(woL + (size_t)(col0 + 16 + r) * 1024) + g + wid * 8;
    f32x4 zz = {0.f, 0.f, 0.f, 0.f};
    f32x4 acc[4] = {zz, zz, zz, zz};
#pragma unroll
    for (int kc = 0; kc < 2; ++kc) {
      bf16x8 a0 = pa0[kc * 4], a1 = pa1[kc * 4];
      bf16x8 b0 = pb0[kc * 4], b1 = pb1[kc * 4];
      acc[0] = __builtin_amdgcn_mfma_f32_16x16x32_bf16(a0, b0, acc[0], 0, 0, 0);
      acc[1] = __builtin_amdgcn_mfma_f32_16x16x32_bf16(a0, b1, acc[1], 0, 0, 0);
      acc[2] = __builtin_amdgcn_mfma_f32_16x16x32_bf16(a1, b0, acc[2], 0, 0, 0);
      acc[3] = __builtin_amdgcn_mfma_f32_16x16x32_bf16(a1, b1, acc[3], 0, 0, 0);
    }
    float* sr = s_red + wid * 1088;
#pragma unroll
    for (int e = 0; e < 4; ++e)
#pragma unroll
      for (int jj = 0; jj < 4; ++jj)
        sr[(((e >> 1) << 4) + (g << 2) + jj) * 34 + ((e & 1) << 4) + r] = acc[e][jj];
  }
  __syncthreads();
  {
    int rrow = tid >> 5, rcol = tid & 31;
    float sum = 0.f;
#pragma unroll
    for (int w = 0; w < 16; ++w) sum += s_red[w * 1088 + rrow * 34 + rcol];
    if (!FINAL) {
      res[(size_t)(row0 + rrow) * 512 + col0 + rcol] += sum;
    } else {
      s_tr[rcol][rrow] = res[(size_t)(row0 + rrow) * 512 + col0 + rcol] + sum;
    }
  }
  if (FINAL) {
    __syncthreads();
    int tl = tid & 31, tc = tid >> 5;
    int b = row0 >> 8, l0 = row0 & 255;
    out[(((size_t)((b << 9) + col0 + tc)) << 8) | (l0 + tl)] = s_tr[tc][tl];
  }
}

// ---------------- launcher ----------------
extern "C" void kernel_launch(void* const* d_in, const int* in_sizes, int n_in,
                              void* d_out, int out_size, void* d_ws, size_t ws_size,
                              hipStream_t stream) {
  (void)in_sizes; (void)n_in; (void)out_size; (void)ws_size;
  const float* x    = (const float*)d_in[0];
  const float* Wi   = (const float*)d_in[1];
  const float* cw   = (const float*)d_in[2];
  const float* cb   = (const float*)d_in[3];
  const float* Wx   = (const float*)d_in[4];
  const float* Wdt  = (const float*)d_in[5];
  const float* bdt  = (const float*)d_in[6];
  const float* Alog = (const float*)d_in[7];
  const float* Dv   = (const float*)d_in[8];
  const float* Wo   = (const float*)d_in[9];
  const float* nw   = (const float*)d_in[10];

  char* ws = (char*)d_ws;
  float*          res    = (float*)(ws + 0);                  // 1 MB
  __hip_bfloat16* xcb    = (__hip_bfloat16*)(ws + 1048576);   // 1 MB
  float*          zT     = (float*)(ws + 4194304);            // 2 MB
  float*          dblraw = (float*)(ws + 6291456);            // 128 KB
  __hip_bfloat16* y      = (__hip_bfloat16*)(ws + 8454144);   // 1 MB
  __hip_bfloat16* wib    = (__hip_bfloat16*)(ws + 10485760);  // 14 MB
  __hip_bfloat16* wxb    = (__hip_bfloat16*)(ws + 25165824);  // 896 KB
  __hip_bfloat16* wob    = (__hip_bfloat16*)(ws + 26083328);  // 7 MB

  k_castin<<<NCASTB + 1024 + 32, 256, 0, stream>>>(Wi, Wx, Wo, x, wib, wxb, wob,
                                                   res, dblraw);

  for (int L = 0; L < NLAYER; ++L) {
    k_front<<<256, 1024, 0, stream>>>(res, nw + L * DIM,
                                      wib + (size_t)L * 2048 * 512,
                                      wxb + (size_t)L * 64 * 1024,
                                      (const float4*)cw + (size_t)L * DINNER,
                                      cb + L * DINNER, xcb, zT, dblraw);
    k_scan<<<256, 1024, 0, stream>>>(dblraw,
                                     Wdt + (size_t)L * DINNER * 32, bdt + L * DINNER,
                                     xcb, zT,
                                     Alog + (size_t)L * DINNER * 16, Dv + L * DINNER, y);
    if (L < NLAYER - 1)
      k_outproj<false><<<256, 1024, 0, stream>>>(y, wob + (size_t)L * 512 * 1024, res,
                                                 nullptr, dblraw);
    else
      k_outproj<true><<<256, 1024, 0, stream>>>(y, wob + (size_t)L * 512 * 1024, res,
                                                (float*)d_out, dblraw);
  }
}

// Round 14
// 301.862 us; speedup vs baseline: 1.4131x; 1.0154x over previous
//
#include <hip/hip_runtime.h>
#include <hip/hip_bf16.h>

typedef __bf16 bf16x8 __attribute__((ext_vector_type(8)));
typedef __bf16 bf16x4 __attribute__((ext_vector_type(4)));
typedef float  f32x4  __attribute__((ext_vector_type(4)));

#define DIM    512
#define DINNER 1024
#define SEQL   256
#define NLAYER 7    // layer 7's mixer output is discarded by the reference
#define LPAD   260  // [.][l] LDS row stride: 260%32==4 -> staggered banks
#define NCH    8
#define CLEN   32

#define N4WI (NLAYER * 2048 * 512 / 4)
#define N4WX (NLAYER * 64 * 1024 / 4)
#define N4WO (NLAYER * 512 * 1024 / 4)
#define N4ALL (N4WI + N4WX + N4WO)          // 2,867,200
#define NCASTB (N4ALL / 256)                // 11200 blocks

// ---------------- merged: weight casts + input transpose + dblraw zero ----------
__global__ __launch_bounds__(256) void k_castin(const float* __restrict__ Wi,
                                                const float* __restrict__ Wx,
                                                const float* __restrict__ Wo,
                                                const float* __restrict__ x,
                                                __hip_bfloat16* __restrict__ wib,
                                                __hip_bfloat16* __restrict__ wxb,
                                                __hip_bfloat16* __restrict__ wob,
                                                float* __restrict__ res,
                                                float* __restrict__ dblraw) {
  if (blockIdx.x >= NCASTB + 1024) {  // zero dblraw[512][64]: 8192 float4, 32 blocks
    int i = (blockIdx.x - NCASTB - 1024) * 256 + threadIdx.x;
    reinterpret_cast<float4*>(dblraw)[i] = float4{0.f, 0.f, 0.f, 0.f};
    return;
  }
  if (blockIdx.x >= NCASTB) {   // transpose region: 1024 blocks
    int idx = (blockIdx.x - NCASTB) * 256 + threadIdx.x;   // B*L*DIM = 262144
    int d = idx & (DIM - 1), l = (idx >> 9) & (SEQL - 1), b = idx >> 17;
    res[idx] = x[((size_t)((b << 9) + d) << 8) + l];
    return;
  }
  int i = blockIdx.x * 256 + threadIdx.x;
  const float* src; __hip_bfloat16* dst; int j;
  if (i < N4WI)             { src = Wi; dst = wib; j = i; }
  else if (i < N4WI + N4WX) { src = Wx; dst = wxb; j = i - N4WI; }
  else                      { src = Wo; dst = wob; j = i - N4WI - N4WX; }
  float4 v = reinterpret_cast<const float4*>(src)[j];
  struct alignas(8) B4 { __hip_bfloat16 a, b, c, d; };
  B4 o{ (__hip_bfloat16)v.x, (__hip_bfloat16)v.y, (__hip_bfloat16)v.z, (__hip_bfloat16)v.w };
  reinterpret_cast<B4*>(dst)[j] = o;
}

// ========== k1: rmsnorm + in_proj + conv + silu + partial x_proj (atomics) ======
// (round-13 verified, unchanged)
__global__ __launch_bounds__(1024) void k_front(const float* __restrict__ res,
                                                const float* __restrict__ nwL,
                                                const __hip_bfloat16* __restrict__ wiL,
                                                const __hip_bfloat16* __restrict__ wxL,
                                                const float4* __restrict__ cwL,
                                                const float* __restrict__ cbL,
                                                __hip_bfloat16* __restrict__ xcb,
                                                float* __restrict__ zT,
                                                float* __restrict__ dblraw) {
  __shared__ __align__(16) char smem[79872];
  __hip_bfloat16 (*s_hn)[520] = (__hip_bfloat16(*)[520])smem;   // 49920B
  float (*s_xz)[132] = (float(*)[132])(smem + 49920);           // 25344B
  __hip_bfloat16 (*s_xcb)[72] = (__hip_bfloat16(*)[72])(smem + 75264); // 4608B
  const int tid = threadIdx.x, bid = blockIdx.x;
  const int wid = tid >> 6, lane = tid & 63;
  const int r = lane & 15, g = lane >> 4;
  const int ttile = bid >> 4, sl = bid & 15;
  const int t0 = ttile * 32, m0 = t0 - 3;
#pragma unroll
  for (int k = 0; k < 3; ++k) {
    int rw = wid * 3 + k;
    int grc = min(max(m0 + rw, 0), 511);
    const float* rr = res + ((size_t)grc << 9);
    float v[8]; float ssum = 0.f;
#pragma unroll
    for (int j2 = 0; j2 < 8; ++j2) { v[j2] = rr[lane + (j2 << 6)]; ssum = fmaf(v[j2], v[j2], ssum); }
#pragma unroll
    for (int m = 1; m < 64; m <<= 1) ssum += __shfl_xor(ssum, m);
    float inv = rsqrtf(ssum * (1.0f / 512.0f) + 1e-5f);
#pragma unroll
    for (int j2 = 0; j2 < 8; ++j2)
      s_hn[rw][lane + (j2 << 6)] = (__hip_bfloat16)(v[j2] * inv * nwL[lane + (j2 << 6)]);
  }
  __syncthreads();
  for (int j = wid; j < 24; j += 16) {
    int mf = j >> 3, cf = j & 7;
    int gcol = (cf < 4) ? (sl * 64 + cf * 16 + r) : (1024 + sl * 64 + (cf - 4) * 16 + r);
    const bf16x8* pb = reinterpret_cast<const bf16x8*>(wiL + (size_t)gcol * 512) + g;
    f32x4 acc = {0.f, 0.f, 0.f, 0.f};
#pragma unroll
    for (int kc = 0; kc < 16; ++kc) {
      bf16x8 a = *reinterpret_cast<const bf16x8*>(&s_hn[mf * 16 + r][kc * 32 + g * 8]);
      acc = __builtin_amdgcn_mfma_f32_16x16x32_bf16(a, pb[kc * 4], acc, 0, 0, 0);
    }
    int cc = (cf < 4) ? (cf * 16 + r) : (64 + (cf - 4) * 16 + r);
#pragma unroll
    for (int jj = 0; jj < 4; ++jj) s_xz[mf * 16 + g * 4 + jj][cc] = acc[jj];
  }
  __syncthreads();
  const int t0s = t0 & 255;
#pragma unroll
  for (int k = 0; k < 2; ++k) {
    int e = tid + (k << 10);
    int lloc = e >> 6, c = e & 63;
    int gd = sl * 64 + c;
    int lseq = t0s + lloc;
    float4 wv = cwL[gd];
    float accv = cbL[gd];
    accv = fmaf(s_xz[lloc + 3][c], wv.w, accv);
    if (lseq >= 1) accv = fmaf(s_xz[lloc + 2][c], wv.z, accv);
    if (lseq >= 2) accv = fmaf(s_xz[lloc + 1][c], wv.y, accv);
    if (lseq >= 3) accv = fmaf(s_xz[lloc + 0][c], wv.x, accv);
    float sv = accv / (1.f + __expf(-accv));
    __hip_bfloat16 hb = (__hip_bfloat16)sv;
    xcb[(size_t)(t0 + lloc) * 1024 + gd] = hb;
    s_xcb[lloc][c] = hb;
  }
  __syncthreads();
  if (wid < 8) {
    int mf = wid & 1, nf = wid >> 1;
    f32x4 acc = {0.f, 0.f, 0.f, 0.f};
#pragma unroll
    for (int kc = 0; kc < 2; ++kc) {
      bf16x8 a = *reinterpret_cast<const bf16x8*>(&s_xcb[mf * 16 + r][kc * 32 + g * 8]);
      bf16x8 bb = *reinterpret_cast<const bf16x8*>(
          wxL + (size_t)(nf * 16 + r) * 1024 + sl * 64 + kc * 32 + g * 8);
      acc = __builtin_amdgcn_mfma_f32_16x16x32_bf16(a, bb, acc, 0, 0, 0);
    }
#pragma unroll
    for (int jj = 0; jj < 4; ++jj)
      atomicAdd(&dblraw[(size_t)(t0 + mf * 16 + g * 4 + jj) * 64 + nf * 16 + r], acc[jj]);
  } else {
#pragma unroll
    for (int k = 0; k < 4; ++k) {
      int e = (tid - 512) + (k << 9);
      int lloc = e & 31, c = e >> 5;
      int gd = sl * 64 + c;
      zT[(size_t)gd * 512 + t0 + lloc] = s_xz[lloc + 3][64 + c];
    }
  }
}

// ========== k2: selective scan v6 — 512 blocks x 512 thr, 4 ch/block ==========
// Same verified math (8 chunks x 32 steps, pair-tree n-reduction); partials in
// registers, s_ys[256][4] only. LDS 49.8KB -> 3 blocks/CU; grid 512 -> 2/CU
// co-resident so serial phases overlap across blocks.
__global__ __launch_bounds__(512) void k_scan(const float* __restrict__ dblraw,
                                              const float* __restrict__ WdtL,
                                              const float* __restrict__ bdtL,
                                              const __hip_bfloat16* __restrict__ xcb,
                                              const float* __restrict__ zT,
                                              const float* __restrict__ alog,
                                              const float* __restrict__ dv,
                                              __hip_bfloat16* __restrict__ y) {
  __shared__ __align__(16) char smem[49792];
  float (*s_dt)[LPAD] = (float(*)[LPAD])(smem);           // [4][260] 4160
  float (*s_xc)[LPAD] = (float(*)[LPAD])(smem + 4160);    // 4160
  float (*s_B)[LPAD]  = (float(*)[LPAD])(smem + 8320);    // [16][260] 16640
  float (*s_C)[LPAD]  = (float(*)[LPAD])(smem + 24960);   // 16640
  float (*s_pe)[64]   = (float(*)[64]) (smem + 41600);    // [8][64] 2048
  float (*s_se)[64]   = (float(*)[64]) (smem + 43648);    // 2048
  float (*s_ys)[4]    = (float(*)[4])  (smem + 45696);    // [256][4] 4096
  const int tid = threadIdx.x, bid = blockIdx.x;
  const int cg = tid >> 6;                 // chunk 0..7
  const int tt = tid & 63;
  const int n = tt & 15, dl = tt >> 4;     // dl 0..3
  const int b = bid >> 8;
  const int d0 = (bid & 255) << 2;
  const int d = d0 + dl;
  const int bL = b * SEQL;

  // stage B,C from dblraw cols 32..63 (4 float4 per thread, coalesced)
#pragma unroll
  for (int k = 0; k < 4; ++k) {
    int fidx = tid + (k << 9);             // 2048
    int l = fidx >> 3, q = fidx & 7;
    float4 v = *reinterpret_cast<const float4*>(dblraw + ((size_t)(bL + l) << 6) + 32 + (q << 2));
    float* dst = (q < 4) ? &s_B[(q & 3) << 2][l] : &s_C[(q & 3) << 2][l];
    dst[0] = v.x; dst[LPAD] = v.y; dst[2 * LPAD] = v.z; dst[3 * LPAD] = v.w;
  }
  // stage xc straight from xcb (bf16, L2-resident): 1 token x 4 ch per thread
  if (tid < 256) {
    bf16x4 u = *reinterpret_cast<const bf16x4*>(xcb + (size_t)(bL + tid) * 1024 + d0);
#pragma unroll
    for (int e = 0; e < 4; ++e) s_xc[e][tid] = (float)u[e];
  }
  // fused dt_proj + softplus from dblraw cols 0..31 (f32, VALU): 2 ch/thread
  {
    int tk = tid >> 1;                     // token 0..255
    int cp = (tid & 1) << 1;               // 0 or 2
    const float* drow = dblraw + ((size_t)(bL + tk) << 6);
    float xv[32];
#pragma unroll
    for (int q = 0; q < 8; ++q) {
      float4 x4 = *reinterpret_cast<const float4*>(drow + (q << 2));
      xv[q * 4 + 0] = x4.x; xv[q * 4 + 1] = x4.y;
      xv[q * 4 + 2] = x4.z; xv[q * 4 + 3] = x4.w;
    }
#pragma unroll
    for (int kk = 0; kk < 2; ++kk) {
      int ch = cp + kk;
      const float4* wr = reinterpret_cast<const float4*>(WdtL + ((size_t)(d0 + ch) << 5));
      float acc = bdtL[d0 + ch];
#pragma unroll
      for (int q = 0; q < 8; ++q) {
        float4 w = wr[q];
        acc = fmaf(xv[q * 4 + 0], w.x, acc);
        acc = fmaf(xv[q * 4 + 1], w.y, acc);
        acc = fmaf(xv[q * 4 + 2], w.z, acc);
        acc = fmaf(xv[q * 4 + 3], w.w, acc);
      }
      s_dt[ch][tk] = (acc > 20.f) ? acc : log1pf(__expf(acc));
    }
  }
  __syncthreads();

  const float An = -__expf(alog[(size_t)d * 16 + n]);
  const int lb = cg << 5;

  // pass 1
  float s = 0.f, P = 1.f;
#pragma unroll 2
  for (int l4 = 0; l4 < CLEN; l4 += 4) {
    const int l = lb + l4;
    float4 dt4 = *reinterpret_cast<const float4*>(&s_dt[dl][l]);
    float4 xc4 = *reinterpret_cast<const float4*>(&s_xc[dl][l]);
    float4 B4  = *reinterpret_cast<const float4*>(&s_B[n][l]);
    float dA;
    dA = __expf(dt4.x * An); P *= dA; s = fmaf(dA, s, dt4.x * xc4.x * B4.x);
    dA = __expf(dt4.y * An); P *= dA; s = fmaf(dA, s, dt4.y * xc4.y * B4.y);
    dA = __expf(dt4.z * An); P *= dA; s = fmaf(dA, s, dt4.z * xc4.z * B4.z);
    dA = __expf(dt4.w * An); P *= dA; s = fmaf(dA, s, dt4.w * xc4.w * B4.w);
  }
  s_pe[cg][tt] = P;
  s_se[cg][tt] = s;
  __syncthreads();

  // exact chunk start state (<=7 iters, wave-uniform)
  float ss = 0.f;
  for (int c = 0; c < cg; ++c) ss = fmaf(s_pe[c][tt], ss, s_se[c][tt]);

  // pass 2: two 16-step halves, partials in registers, shfl pair-tree reduce
  float s2 = ss;
#pragma unroll
  for (int half = 0; half < 2; ++half) {
    const int base = lb + (half << 4);
    float cr[16];
#pragma unroll
    for (int l4 = 0; l4 < 16; l4 += 4) {
      const int l = base + l4;
      float4 dt4 = *reinterpret_cast<const float4*>(&s_dt[dl][l]);
      float4 xc4 = *reinterpret_cast<const float4*>(&s_xc[dl][l]);
      float4 B4  = *reinterpret_cast<const float4*>(&s_B[n][l]);
      float4 C4  = *reinterpret_cast<const float4*>(&s_C[n][l]);
      float dA;
      dA = __expf(dt4.x * An); s2 = fmaf(dA, s2, dt4.x * xc4.x * B4.x); cr[l4 + 0] = s2 * C4.x;
      dA = __expf(dt4.y * An); s2 = fmaf(dA, s2, dt4.y * xc4.y * B4.y); cr[l4 + 1] = s2 * C4.y;
      dA = __expf(dt4.z * An); s2 = fmaf(dA, s2, dt4.z * xc4.z * B4.z); cr[l4 + 2] = s2 * C4.z;
      dA = __expf(dt4.w * An); s2 = fmaf(dA, s2, dt4.w * xc4.w * B4.w); cr[l4 + 3] = s2 * C4.w;
    }
#pragma unroll
    for (int i = 0; i < 16; ++i) {
      float c = cr[i];
      c += __shfl_xor(c, 1);
      c += __shfl_xor(c, 2);
      c += __shfl_xor(c, 4);
      c += __shfl_xor(c, 8);
      cr[i] = c;
    }
    if (n == 0) {
#pragma unroll
      for (int i = 0; i < 16; ++i) s_ys[base + i][dl] = cr[i];
    }
  }
  __syncthreads();

  // epilogue: gate + store (1024 outputs, 2 per thread, coalesced)
#pragma unroll
  for (int k = 0; k < 2; ++k) {
    int idx = tid + (k << 9);
    int l = idx >> 2, dd = idx & 3;
    float sum = s_ys[l][dd];
    float xcv = s_xc[dd][l];
    float zv = zT[(size_t)(d0 + dd) * 512 + bL + l];
    float yv = (sum + dv[d0 + dd] * xcv) * (zv / (1.f + __expf(-zv)));
    y[((size_t)(bL + l) << 10) + d0 + dd] = (__hip_bfloat16)yv;
  }
}

// ========== k3: out_proj (+residual | final transposed out) + dblraw zeroing ====
template <bool FINAL>
__global__ __launch_bounds__(1024) void k_outproj(const __hip_bfloat16* __restrict__ y,
                                                  const __hip_bfloat16* __restrict__ woL,
                                                  float* __restrict__ res,
                                                  float* __restrict__ out,
                                                  float* __restrict__ dblraw) {
  __shared__ __align__(16) float s_red[16 * 1088 + 32 * 33];
  float (*s_tr)[33] = (float(*)[33])(s_red + 16 * 1088);
  const int tid = threadIdx.x, bid = blockIdx.x;
  const int wid = tid >> 6, lane = tid & 63;
  const int r = lane & 15, g = lane >> 4;
  int tile = bid >> 2, q = bid & 3;
  int row0 = (tile >> 3) * 64 + ((q >> 1) << 5);
  int col0 = (tile & 7) * 64 + ((q & 1) << 5);
  if (!FINAL && tid < 32)
    reinterpret_cast<float4*>(dblraw)[bid * 32 + tid] = float4{0.f, 0.f, 0.f, 0.f};
  {
    const bf16x8* pa0 = reinterpret_cast<const bf16x8*>(y + (size_t)(row0 + r) * 1024) + g + wid * 8;
    const bf16x8* pa1 = reinterpret_cast<const bf16x8*>(y + (size_t)(row0 + 16 + r) * 1024) + g + wid * 8;
    const bf16x8* pb0 = reinterpret_cast<const bf16x8*>(woL + (size_t)(col0 + r) * 1024) + g + wid * 8;
    const bf16x8* pb1 = reinterpret_cast<const bf16x8*>(woL + (size_t)(col0 + 16 + r) * 1024) + g + wid * 8;
    f32x4 zz = {0.f, 0.f, 0.f, 0.f};
    f32x4 acc[4] = {zz, zz, zz, zz};
#pragma unroll
    for (int kc = 0; kc < 2; ++kc) {
      bf16x8 a0 = pa0[kc * 4], a1 = pa1[kc * 4];
      bf16x8 b0 = pb0[kc * 4], b1 = pb1[kc * 4];
      acc[0] = __builtin_amdgcn_mfma_f32_16x16x32_bf16(a0, b0, acc[0], 0, 0, 0);
      acc[1] = __builtin_amdgcn_mfma_f32_16x16x32_bf16(a0, b1, acc[1], 0, 0, 0);
      acc[2] = __builtin_amdgcn_mfma_f32_16x16x32_bf16(a1, b0, acc[2], 0, 0, 0);
      acc[3] = __builtin_amdgcn_mfma_f32_16x16x32_bf16(a1, b1, acc[3], 0, 0, 0);
    }
    float* sr = s_red + wid * 1088;
#pragma unroll
    for (int e = 0; e < 4; ++e)
#pragma unroll
      for (int jj = 0; jj < 4; ++jj)
        sr[(((e >> 1) << 4) + (g << 2) + jj) * 34 + ((e & 1) << 4) + r] = acc[e][jj];
  }
  __syncthreads();
  {
    int rrow = tid >> 5, rcol = tid & 31;
    float sum = 0.f;
#pragma unroll
    for (int w = 0; w < 16; ++w) sum += s_red[w * 1088 + rrow * 34 + rcol];
    if (!FINAL) {
      res[(size_t)(row0 + rrow) * 512 + col0 + rcol] += sum;
    } else {
      s_tr[rcol][rrow] = res[(size_t)(row0 + rrow) * 512 + col0 + rcol] + sum;
    }
  }
  if (FINAL) {
    __syncthreads();
    int tl = tid & 31, tc = tid >> 5;
    int b = row0 >> 8, l0 = row0 & 255;
    out[(((size_t)((b << 9) + col0 + tc)) << 8) | (l0 + tl)] = s_tr[tc][tl];
  }
}

// ---------------- launcher ----------------
extern "C" void kernel_launch(void* const* d_in, const int* in_sizes, int n_in,
                              void* d_out, int out_size, void* d_ws, size_t ws_size,
                              hipStream_t stream) {
  (void)in_sizes; (void)n_in; (void)out_size; (void)ws_size;
  const float* x    = (const float*)d_in[0];
  const float* Wi   = (const float*)d_in[1];
  const float* cw   = (const float*)d_in[2];
  const float* cb   = (const float*)d_in[3];
  const float* Wx   = (const float*)d_in[4];
  const float* Wdt  = (const float*)d_in[5];
  const float* bdt  = (const float*)d_in[6];
  const float* Alog = (const float*)d_in[7];
  const float* Dv   = (const float*)d_in[8];
  const float* Wo   = (const float*)d_in[9];
  const float* nw   = (const float*)d_in[10];

  char* ws = (char*)d_ws;
  float*          res    = (float*)(ws + 0);                  // 1 MB
  __hip_bfloat16* xcb    = (__hip_bfloat16*)(ws + 1048576);   // 1 MB
  float*          zT     = (float*)(ws + 4194304);            // 2 MB
  float*          dblraw = (float*)(ws + 6291456);            // 128 KB
  __hip_bfloat16* y      = (__hip_bfloat16*)(ws + 8454144);   // 1 MB
  __hip_bfloat16* wib    = (__hip_bfloat16*)(ws + 10485760);  // 14 MB
  __hip_bfloat16* wxb    = (__hip_bfloat16*)(ws + 25165824);  // 896 KB
  __hip_bfloat16* wob    = (__hip_bfloat16*)(ws + 26083328);  // 7 MB

  k_castin<<<NCASTB + 1024 + 32, 256, 0, stream>>>(Wi, Wx, Wo, x, wib, wxb, wob,
                                                   res, dblraw);

  for (int L = 0; L < NLAYER; ++L) {
    k_front<<<256, 1024, 0, stream>>>(res, nw + L * DIM,
                                      wib + (size_t)L * 2048 * 512,
                                      wxb + (size_t)L * 64 * 1024,
                                      (const float4*)cw + (size_t)L * DINNER,
                                      cb + L * DINNER, xcb, zT, dblraw);
    k_scan<<<512, 512, 0, stream>>>(dblraw,
                                    Wdt + (size_t)L * DINNER * 32, bdt + L * DINNER,
                                    xcb, zT,
                                    Alog + (size_t)L * DINNER * 16, Dv + L * DINNER, y);
    if (L < NLAYER - 1)
      k_outproj<false><<<256, 1024, 0, stream>>>(y, wob + (size_t)L * 512 * 1024, res,
                                                 nullptr, dblraw);
    else
      k_outproj<true><<<256, 1024, 0, stream>>>(y, wob + (size_t)L * 512 * 1024, res,
                                                (float*)d_out, dblraw);
  }
}